// Round 16
// baseline (188.952 us; speedup 1.0000x reference)
//
#include <hip/hip_runtime.h>
#include <hip/hip_bf16.h>
#include <stdint.h>

#define M_DIM 8192
#define N_DIM 4096
#define K_DIM 4096

#define BM 256
#define BN 256
#define BK 64                 // bytes of K per tile = one mfma_i32_16x16x64_i8 K
#define NT (K_DIM / BK)       // 64 K-tiles
#define DEPTH 4               // circular LDS pipeline depth (A only)

typedef int v4i __attribute__((ext_vector_type(4)));

#define AS1C(p) ((const __attribute__((address_space(1))) void*)(p))
#define AS3(p)  ((__attribute__((address_space(3))) void*)(p))

// ---------------------------------------------------------------------------
// Pack pass.  A: linear int8 (as before).  B: FRAGMENT-TILED int8 layout —
// chunk index j = (g*64 + t)*64 + l   (g = n-tile of 16 rows, t = K-tile,
// l = lane) holds bytes B[n = g*16 + (l&15)][k = t*64 + (l>>4)*16 .. +16).
// A wave's B-fragment load is then ONE contiguous 1 KB global read
// (lane l at byte l*16) — fixes R11's 4KB-strided uncoalesced pattern.
// ---------------------------------------------------------------------------
__device__ __forceinline__ int pack4(int a, int b, int c, int d) {
  return (a & 0xff) | ((b & 0xff) << 8) | ((c & 0xff) << 16) | (d << 24);
}

__global__ void pack_both_kernel(const int* __restrict__ x, const int* __restrict__ w,
                                 char* __restrict__ A8, char* __restrict__ B8,
                                 int nA, int nTot) {
  int idx = blockIdx.x * blockDim.x + threadIdx.x;
  int stride = gridDim.x * blockDim.x;
  for (int i = idx; i < nTot; i += stride) {
    const int4* pin;
    if (i < nA) {
      pin = (const int4*)x + 4 * (size_t)i;         // A: linear
    } else {
      int j = i - nA;                               // B: tiled
      int l = j & 63;
      int t = (j >> 6) & 63;
      int g = j >> 12;
      int n  = g * 16 + (l & 15);
      int k0 = t * 64 + (l >> 4) * 16;
      pin = (const int4*)(w + (size_t)n * K_DIM + k0);
    }
    int4 v0 = pin[0];
    int4 v1 = pin[1];
    int4 v2 = pin[2];
    int4 v3 = pin[3];
    int4 o;
    o.x = pack4(v0.x, v0.y, v0.z, v0.w);
    o.y = pack4(v1.x, v1.y, v1.z, v1.w);
    o.z = pack4(v2.x, v2.y, v2.z, v2.w);
    o.w = pack4(v3.x, v3.y, v3.z, v3.w);
    if (i < nA) ((int4*)A8)[i] = o;
    else        ((int4*)B8)[i - nA] = o;
  }
}

// ---------------------------------------------------------------------------
// int8 GEMM: 256x256 tile, 8 waves (2Mx4N, per-wave 128x64), BK=64B,
// mfma_i32_16x16x64_i8.  R16 = R15 (anti-phased waves, cross-tile register
// prefetch, counted vmcnt, setprio) with B MOVED OUT OF LDS:
//   - A staged via DEPTH=4 LDS ring (64 KiB), verified conflict-free swizzle.
//   - B loaded global->register from the fragment-tiled B8 layout:
//     one coalesced 1KB global_load_dwordx4 per frag, prefetched one tile
//     ahead into ping-pong sets; L2-resident (row-major XCD walk gives each
//     XCD a 2 MiB B slice < 4 MiB L2).
// Per CU/tile: LDS reads 96->64 b128, stage writes 32->16 KB  => LDS pipe
// (~900 cyc) now well under MFMA (1306 cyc); VMEM ~860 cyc on its own pipe.
//
//   even waves: BLOAD(t+1); STAGE_A(t+3); READ_AHI(t); MFMA_LO(t);
//               READ_ALO(t+1); MFMA_HI(t); vmcnt(6); barrier
//   odd waves:  MFMA_LO first (anti-phase, R15 +3%).
//
// Wait math: end-of-t queue (oldest first) = sA(t+2):2, bl(t+1):4, sA(t+3):2.
// vmcnt(6) drains sA(t+2) -> A(t+2) proven before its reads during t+1.
// bl(t+1) registers guarded by compiler operand waits before MFMA_LO(t+1).
// STAGE_A(t+3) overwrites A-buf[(t-1)&3]; its reads finished during t-2.
// ---------------------------------------------------------------------------
__global__ __launch_bounds__(512, 2) void gemm_i8_kernel(
    const char* __restrict__ A8, const char* __restrict__ B8,
    const int* __restrict__ bias, const float* __restrict__ alpha_p,
    const float* __restrict__ beta_p, int* __restrict__ out) {
  __shared__ alignas(16) char lds[DEPTH][BM * BK];  // 4 x 16 KiB = 64 KiB

  const int tid  = threadIdx.x;
  const int lane = tid & 63;
  const int wave = tid >> 6;

  // XCD swizzle, row-major walk: xcd = orig&7 gets col-tiles {2x, 2x+1}
  // (2 MiB of tiled B8, L2-resident) x 32 row-tiles.
  const int orig = blockIdx.x;
  const int xcd  = orig & 7;
  const int j    = orig >> 3;          // 0..63 within XCD
  const int bm   = (j & 31) * BM;      // 32 row-tiles, walks fast
  const int bn   = (xcd * 2 + (j >> 5)) * BN;  // 16 col-tiles

  // A staging: tile 16 KB = 2 rounds x 512 thr x 16 B.
  // Pre-swizzled global chunk g = p ^ ((row>>1)&3) (both-sides swizzle).
  int aoff[2], ldsoff[2];
#pragma unroll
  for (int i = 0; i < 2; ++i) {
    int linear = i * 8192 + tid * 16;
    int row = linear >> 6;           // 64 B rows
    int p   = (linear >> 4) & 3;
    int g   = p ^ ((row >> 1) & 3);
    ldsoff[i] = i * 8192 + wave * 1024;       // wave-uniform LDS base
    aoff[i] = (bm + row) * K_DIM + g * 16;
  }

#define STAGE_A(t)                                                                  \
  do {                                                                              \
    const char* ab_ = A8 + (size_t)(t) * BK;                                        \
    char* base_ = &lds[(t) & (DEPTH - 1)][0];                                       \
    _Pragma("unroll") for (int i_ = 0; i_ < 2; ++i_)                                \
      __builtin_amdgcn_global_load_lds(AS1C(ab_ + aoff[i_]),                        \
                                       AS3(base_ + ldsoff[i_]), 16, 0, 0);          \
  } while (0)

  v4i acc[8][4];
#pragma unroll
  for (int i = 0; i < 8; ++i)
#pragma unroll
    for (int jj = 0; jj < 4; ++jj) acc[i][jj] = (v4i){0, 0, 0, 0};

  const int wr = wave >> 2;         // 0..1 (M half: 128 rows)
  const int wc = wave & 3;          // 0..3 (N quarter: 64 cols)
  const int frow = lane & 15;
  const int fchunk = lane >> 4;
  // swizzle XOR depends only on frow (rows differ by multiples of 16) -> lane-const
  const int swzoff = ((fchunk ^ ((frow >> 1) & 3)) << 4);

  // B tiled base: this wave's first n-tile g0 = bn/16 + wc*4; lane offset l*16.
  // Frag (g0+nj, t) at B8 + (g0+nj)*65536 + t*1024 + lane*16.
  const char* Btp = B8 + (size_t)(bn / 16 + wc * 4) * 65536 + lane * 16;

  // Ping-pong fragment sets (static names, rule #20) + shared afhi.
  v4i bf0[4], aflo0[4], bf1[4], aflo1[4], afhi[4];

#define BLOAD(S, t)                                                                 \
  do {                                                                              \
    _Pragma("unroll") for (int nj = 0; nj < 4; ++nj)                                \
      bf##S[nj] = *(const v4i*)(Btp + nj * 65536 + (t) * 1024);                     \
  } while (0)

#define READ_ALO(S, t)                                                              \
  do {                                                                              \
    const char* base_ = &lds[(t) & (DEPTH - 1)][0];                                 \
    _Pragma("unroll") for (int mi = 0; mi < 4; ++mi)                                \
      aflo##S[mi] = *(const v4i*)(base_ + (wr * 128 + mi * 16 + frow) * 64 +        \
                                  swzoff);                                          \
  } while (0)

#define READ_AHI(t)                                                                 \
  do {                                                                              \
    const char* base_ = &lds[(t) & (DEPTH - 1)][0];                                 \
    _Pragma("unroll") for (int mi = 0; mi < 4; ++mi)                                \
      afhi[mi] = *(const v4i*)(base_ + (wr * 128 + (mi + 4) * 16 + frow) * 64 +     \
                               swzoff);                                             \
  } while (0)

#define MFMA_LO(S)                                                                  \
  do {                                                                              \
    __builtin_amdgcn_s_setprio(1);                                                  \
    _Pragma("unroll") for (int mi = 0; mi < 4; ++mi)                                \
      _Pragma("unroll") for (int nj = 0; nj < 4; ++nj)                              \
        acc[mi][nj] = __builtin_amdgcn_mfma_i32_16x16x64_i8(aflo##S[mi], bf##S[nj], \
                                                            acc[mi][nj], 0, 0, 0); \
    __builtin_amdgcn_s_setprio(0);                                                  \
  } while (0)

#define MFMA_HI(S)                                                                  \
  do {                                                                              \
    __builtin_amdgcn_s_setprio(1);                                                  \
    _Pragma("unroll") for (int mi = 0; mi < 4; ++mi)                                \
      _Pragma("unroll") for (int nj = 0; nj < 4; ++nj)                              \
        acc[mi + 4][nj] = __builtin_amdgcn_mfma_i32_16x16x64_i8(afhi[mi], bf##S[nj],\
                                                                acc[mi + 4][nj],   \
                                                                0, 0, 0);          \
    __builtin_amdgcn_s_setprio(0);                                                  \
  } while (0)

#define EVWAIT(EV)                                                                  \
  do {                                                                              \
    if ((EV) == 6) asm volatile("s_waitcnt vmcnt(6)" ::: "memory");                 \
    if ((EV) == 4) asm volatile("s_waitcnt vmcnt(4)" ::: "memory");                 \
    if ((EV) == 0) asm volatile("s_waitcnt vmcnt(0)" ::: "memory");                 \
    if ((EV) >= 0) __builtin_amdgcn_s_barrier();                                    \
  } while (0)

// Even group: loads/reads first, MFMA second.
#define TILE_E(t, C, N, DOBL, DOSTG, EV)                                            \
  do {                                                                              \
    if (DOBL) BLOAD(N, (t) + 1);                                                    \
    if (DOSTG) STAGE_A((t) + 3);                                                    \
    READ_AHI(t);                                                                    \
    MFMA_LO(C);                                                                     \
    if ((t) + 1 < NT) READ_ALO(N, (t) + 1);                                         \
    MFMA_HI(C);                                                                     \
    EVWAIT(EV);                                                                     \
  } while (0)

// Odd group: MFMA first (anti-phase).
#define TILE_O(t, C, N, DOBL, DOSTG, EV)                                            \
  do {                                                                              \
    MFMA_LO(C);                                                                     \
    if (DOBL) BLOAD(N, (t) + 1);                                                    \
    if (DOSTG) STAGE_A((t) + 3);                                                    \
    READ_AHI(t);                                                                    \
    MFMA_HI(C);                                                                     \
    if ((t) + 1 < NT) READ_ALO(N, (t) + 1);                                         \
    EVWAIT(EV);                                                                     \
  } while (0)

  // Prologue: stage A 0..2 (6 vm), bload B tile 0 (4 vm);
  // vmcnt(6) -> A0,A1 landed; barrier; read tile-0 A-lo frags.
  STAGE_A(0);
  STAGE_A(1);
  STAGE_A(2);
  BLOAD(0, 0);
  asm volatile("s_waitcnt vmcnt(6)" ::: "memory");
  __builtin_amdgcn_s_barrier();
  READ_ALO(0, 0);

  if ((wave & 4) == 0) {
    for (int t = 0; t < NT - 4; t += 2) {   // t=0..58: stages 3..61, bloads 1..60
      TILE_E(t, 0, 1, true, true, 6);
      TILE_E(t + 1, 1, 0, true, true, 6);
    }
    TILE_E(NT - 4, 0, 1, true, true, 6);    // t=60: stage 63, bload 61
    TILE_E(NT - 3, 1, 0, true, false, 4);   // t=61: bload 62; sA63 proven
    TILE_E(NT - 2, 0, 1, true, false, 0);   // t=62: bload 63
    TILE_E(NT - 1, 1, 0, false, false, -1); // t=63
  } else {
    for (int t = 0; t < NT - 4; t += 2) {
      TILE_O(t, 0, 1, true, true, 6);
      TILE_O(t + 1, 1, 0, true, true, 6);
    }
    TILE_O(NT - 4, 0, 1, true, true, 6);
    TILE_O(NT - 3, 1, 0, true, false, 4);
    TILE_O(NT - 2, 0, 1, true, false, 0);
    TILE_O(NT - 1, 1, 0, false, false, -1);
  }

  // Epilogue: D = rint(alpha*acc + beta*bias[n]).
  // C/D layout (16x16): col = lane&15, row = (lane>>4)*4 + reg.
  const float alpha = *alpha_p;
  const float beta  = *beta_p;
  const int col0 = bn + wc * 64 + frow;
  float bb4[4];
#pragma unroll
  for (int nj = 0; nj < 4; ++nj) bb4[nj] = beta * (float)bias[col0 + nj * 16];

  const int rbase = bm + wr * 128 + (lane >> 4) * 4;
#pragma unroll
  for (int mi = 0; mi < 8; ++mi) {
#pragma unroll
    for (int r = 0; r < 4; ++r) {
      size_t rowoff = (size_t)(rbase + mi * 16 + r) * N_DIM;
#pragma unroll
      for (int nj = 0; nj < 4; ++nj) {
        out[rowoff + col0 + nj * 16] =
            (int)rintf(fmaf(alpha, (float)acc[mi][nj][r], bb4[nj]));
      }
    }
  }
#undef STAGE_A
#undef BLOAD
#undef READ_ALO
#undef READ_AHI
#undef MFMA_LO
#undef MFMA_HI
#undef EVWAIT
#undef TILE_E
#undef TILE_O
}

// ---------------------------------------------------------------------------
// Safety fallback if ws is too small for the packed operands (slow but right).
// ---------------------------------------------------------------------------
__global__ void naive_kernel(const int* __restrict__ x, const int* __restrict__ w,
                             const int* __restrict__ bias,
                             const float* __restrict__ alpha_p,
                             const float* __restrict__ beta_p,
                             int* __restrict__ out) {
  size_t idx = (size_t)blockIdx.x * 256 + threadIdx.x;
  int m = (int)(idx / N_DIM);
  int n = (int)(idx % N_DIM);
  const int4* xr = (const int4*)(x + (size_t)m * K_DIM);
  const int4* wr = (const int4*)(w + (size_t)n * K_DIM);
  int acc = 0;
  for (int k = 0; k < K_DIM / 4; ++k) {
    int4 a = xr[k];
    int4 b = wr[k];
    acc += a.x * b.x + a.y * b.y + a.z * b.z + a.w * b.w;
  }
  out[idx] = (int)rintf(fmaf(*alpha_p, (float)acc, (*beta_p) * (float)bias[n]));
}

extern "C" void kernel_launch(void* const* d_in, const int* in_sizes, int n_in,
                              void* d_out, int out_size, void* d_ws, size_t ws_size,
                              hipStream_t stream) {
  const int*   x     = (const int*)d_in[0];
  const int*   w     = (const int*)d_in[1];
  const int*   bias  = (const int*)d_in[2];
  const float* alpha = (const float*)d_in[3];
  const float* beta  = (const float*)d_in[4];
  int* out = (int*)d_out;

  const size_t a8_bytes = (size_t)M_DIM * K_DIM;  // 32 MiB
  const size_t b8_bytes = (size_t)N_DIM * K_DIM;  // 16 MiB

  if (ws_size >= a8_bytes + b8_bytes) {
    char* A8 = (char*)d_ws;
    char* B8 = A8 + a8_bytes;
    const int nA = (int)(a8_bytes / 16);
    const int nTot = (int)((a8_bytes + b8_bytes) / 16);
    pack_both_kernel<<<2048, 256, 0, stream>>>(x, w, A8, B8, nA, nTot);
    const int nblk = (M_DIM / BM) * (N_DIM / BN);  // 32*16 = 512
    gemm_i8_kernel<<<nblk, 512, 0, stream>>>(A8, B8, bias, alpha, beta, out);
  } else {
    naive_kernel<<<(M_DIM * (size_t)N_DIM) / 256, 256, 0, stream>>>(x, w, bias, alpha, beta, out);
  }
}

// Round 17
// 184.672 us; speedup vs baseline: 1.0232x; 1.0232x over previous
//
#include <hip/hip_runtime.h>
#include <hip/hip_bf16.h>
#include <stdint.h>

#define M_DIM 8192
#define N_DIM 4096
#define K_DIM 4096

#define BM 256
#define BN 256
#define BK 64                 // bytes of K per LDS tile = one mfma_i32_16x16x64_i8 K
#define NT (K_DIM / BK)       // 64 K-tiles
#define DEPTH 4               // circular LDS pipeline depth
#define RND_DELTA (16 * BM * K_DIM)   // A-offset delta between the two rounds

typedef int v4i __attribute__((ext_vector_type(4)));

#define AS1C(p) ((const __attribute__((address_space(1))) void*)(p))
#define AS3(p)  ((__attribute__((address_space(3))) void*)(p))

// ---------------------------------------------------------------------------
// Fused pack pass: int32 (int8-range) -> int8 for BOTH operands, one launch.
// (Linear layouts — R16's fragment-tiled B reverted with the B-in-reg path.)
// ---------------------------------------------------------------------------
__device__ __forceinline__ int pack4(int a, int b, int c, int d) {
  return (a & 0xff) | ((b & 0xff) << 8) | ((c & 0xff) << 16) | (d << 24);
}

__global__ void pack_both_kernel(const int* __restrict__ x, const int* __restrict__ w,
                                 char* __restrict__ A8, char* __restrict__ B8,
                                 int nA, int nTot) {
  int idx = blockIdx.x * blockDim.x + threadIdx.x;
  int stride = gridDim.x * blockDim.x;
  for (int i = idx; i < nTot; i += stride) {
    const int4* pin;
    int4* pout;
    if (i < nA) {
      pin  = (const int4*)x + 4 * (size_t)i;
      pout = (int4*)A8 + i;
    } else {
      int j = i - nA;
      pin  = (const int4*)w + 4 * (size_t)j;
      pout = (int4*)B8 + j;
    }
    int4 v0 = pin[0];
    int4 v1 = pin[1];
    int4 v2 = pin[2];
    int4 v3 = pin[3];
    int4 o;
    o.x = pack4(v0.x, v0.y, v0.z, v0.w);
    o.y = pack4(v1.x, v1.y, v1.z, v1.w);
    o.z = pack4(v2.x, v2.y, v2.z, v2.w);
    o.w = pack4(v3.x, v3.y, v3.z, v3.w);
    *pout = o;
  }
}

// ---------------------------------------------------------------------------
// R17 = R15 champion (anti-phased waves, cross-tile register prefetch,
// counted vmcnt, setprio, conflict-free both-sides LDS swizzle) made
// PERSISTENT over TWO row-tiles: 256 blocks, each computes (bm, bn) then
// (bm + 16*BM, bn).  Round-1's prologue stages are issued BEFORE round-0's
// epilogue, so the ~10us of C-stores hides the staging latency and the
// round transition costs one vmcnt(0)+barrier instead of a block launch.
// B-panel + bias reused across rounds via L2 (16 blocks/XCD share one bn).
//
// Round seam safety: K-loop tail exits with all own gloads drained
// (vmcnt(0) at t=NT-3, no stages after) and all ds_reads consumed by MFMA
// operand waits; one barrier then makes buf[0..2] safe to re-stage.  The
// re-staged loads land during the epilogue; vmcnt(0)+barrier before
// round-1's READ0 covers both the stores and the stage loads.
// ---------------------------------------------------------------------------
__global__ __launch_bounds__(512, 2) void gemm_i8_kernel(
    const char* __restrict__ A8, const char* __restrict__ B8,
    const int* __restrict__ bias, const float* __restrict__ alpha_p,
    const float* __restrict__ beta_p, int* __restrict__ out) {
  __shared__ alignas(16) char lds[DEPTH][BM * BK + BN * BK];  // 4 x 32 KiB

  const int tid  = threadIdx.x;
  const int lane = tid & 63;
  const int wave = tid >> 6;

  // 256 blocks: xcd = orig&7; within-XCD 32 blocks = 2 bn x 16 bm-pairs.
  // Each XCD's 2 B-panels (2 MiB packed) stay L2-resident across the run.
  const int orig = blockIdx.x;
  const int xcd  = orig & 7;
  const int j    = orig >> 3;                  // 0..31
  const int bn   = (xcd * 2 + (j >> 4)) * BN;  // 16 col-tiles
  int       bm   = (j & 15) * BM;              // round 0: rows 0..15; +16 later

  // Staging geometry: per operand tile 16 KB = 2 rounds x 512 thr x 16 B.
  // Pre-swizzled global chunk g = p ^ ((row>>1)&3) (both-sides swizzle).
  int aoff[2], boff[2], ldsoff[2];
#pragma unroll
  for (int i = 0; i < 2; ++i) {
    int linear = i * 8192 + tid * 16;
    int row = linear >> 6;           // 64 B rows
    int p   = (linear >> 4) & 3;
    int g   = p ^ ((row >> 1) & 3);
    ldsoff[i] = i * 8192 + wave * 1024;       // wave-uniform LDS base
    aoff[i] = (bm + row) * K_DIM + g * 16;
    boff[i] = (bn + row) * K_DIM + g * 16;
  }

#define STAGE_A(t)                                                                  \
  do {                                                                              \
    const char* ab_ = A8 + (size_t)(t) * BK;                                        \
    char* base_ = &lds[(t) & (DEPTH - 1)][0];                                       \
    _Pragma("unroll") for (int i_ = 0; i_ < 2; ++i_)                                \
      __builtin_amdgcn_global_load_lds(AS1C(ab_ + aoff[i_]),                        \
                                       AS3(base_ + ldsoff[i_]), 16, 0, 0);          \
  } while (0)

#define STAGE_B(t)                                                                  \
  do {                                                                              \
    const char* bb_ = B8 + (size_t)(t) * BK;                                        \
    char* base_ = &lds[(t) & (DEPTH - 1)][0];                                       \
    _Pragma("unroll") for (int i_ = 0; i_ < 2; ++i_)                                \
      __builtin_amdgcn_global_load_lds(AS1C(bb_ + boff[i_]),                        \
                                       AS3(base_ + 16384 + ldsoff[i_]), 16, 0, 0);  \
  } while (0)

  v4i acc[8][4];
#pragma unroll
  for (int i = 0; i < 8; ++i)
#pragma unroll
    for (int jj = 0; jj < 4; ++jj) acc[i][jj] = (v4i){0, 0, 0, 0};

  const int wr = wave >> 2;         // 0..1 (M half: 128 rows)
  const int wc = wave & 3;          // 0..3 (N quarter: 64 cols)
  const int frow = lane & 15;
  const int fchunk = lane >> 4;
  // swizzle XOR depends only on frow (rows differ by multiples of 16) -> lane-const
  const int swzoff = ((fchunk ^ ((frow >> 1) & 3)) << 4);

  // Ping-pong lo-fragment sets (static names, rule #20) + shared afhi.
  v4i bf0[4], aflo0[4], bf1[4], aflo1[4], afhi[4];

#define READ0(S, t)                                                                 \
  do {                                                                              \
    const char* base_ = &lds[(t) & (DEPTH - 1)][0];                                 \
    _Pragma("unroll") for (int nj = 0; nj < 4; ++nj)                                \
      bf##S[nj] = *(const v4i*)(base_ + 16384 + (wc * 64 + nj * 16 + frow) * 64 +   \
                                swzoff);                                            \
    _Pragma("unroll") for (int mi = 0; mi < 4; ++mi)                                \
      aflo##S[mi] = *(const v4i*)(base_ + (wr * 128 + mi * 16 + frow) * 64 +        \
                                  swzoff);                                          \
  } while (0)

#define READ1(t)                                                                    \
  do {                                                                              \
    const char* base_ = &lds[(t) & (DEPTH - 1)][0];                                 \
    _Pragma("unroll") for (int mi = 0; mi < 4; ++mi)                                \
      afhi[mi] = *(const v4i*)(base_ + (wr * 128 + (mi + 4) * 16 + frow) * 64 +     \
                               swzoff);                                             \
  } while (0)

#define MFMA_LO(S)                                                                  \
  do {                                                                              \
    __builtin_amdgcn_s_setprio(1);                                                  \
    _Pragma("unroll") for (int mi = 0; mi < 4; ++mi)                                \
      _Pragma("unroll") for (int nj = 0; nj < 4; ++nj)                              \
        acc[mi][nj] = __builtin_amdgcn_mfma_i32_16x16x64_i8(aflo##S[mi], bf##S[nj], \
                                                            acc[mi][nj], 0, 0, 0); \
    __builtin_amdgcn_s_setprio(0);                                                  \
  } while (0)

#define MFMA_HI(S)                                                                  \
  do {                                                                              \
    __builtin_amdgcn_s_setprio(1);                                                  \
    _Pragma("unroll") for (int mi = 0; mi < 4; ++mi)                                \
      _Pragma("unroll") for (int nj = 0; nj < 4; ++nj)                              \
        acc[mi + 4][nj] = __builtin_amdgcn_mfma_i32_16x16x64_i8(afhi[mi], bf##S[nj],\
                                                                acc[mi + 4][nj],   \
                                                                0, 0, 0);          \
    __builtin_amdgcn_s_setprio(0);                                                  \
  } while (0)

#define EVWAIT(EV)                                                                  \
  do {                                                                              \
    if ((EV) == 4) asm volatile("s_waitcnt vmcnt(4)" ::: "memory");                 \
    if ((EV) == 0) asm volatile("s_waitcnt vmcnt(0)" ::: "memory");                 \
    if ((EV) >= 0) __builtin_amdgcn_s_barrier();                                    \
  } while (0)

// Even group: LDS first, MFMA second.
#define TILE_E(t, C, N, STG, EV)                                                    \
  do {                                                                              \
    if (STG) STAGE_A((t) + 3);                                                      \
    READ1(t);                                                                       \
    MFMA_LO(C);                                                                     \
    if (STG) STAGE_B((t) + 3);                                                      \
    if ((t) + 1 < NT) READ0(N, (t) + 1);                                            \
    MFMA_HI(C);                                                                     \
    EVWAIT(EV);                                                                     \
  } while (0)

// Odd group: MFMA first, LDS second (anti-phase; R15 +3%).
#define TILE_O(t, C, N, STG, EV)                                                    \
  do {                                                                              \
    MFMA_LO(C);                                                                     \
    if (STG) STAGE_A((t) + 3);                                                      \
    READ1(t);                                                                       \
    MFMA_HI(C);                                                                     \
    if (STG) STAGE_B((t) + 3);                                                      \
    if ((t) + 1 < NT) READ0(N, (t) + 1);                                            \
    EVWAIT(EV);                                                                     \
  } while (0)

#define KLOOP_E()                                                                   \
  do {                                                                              \
    for (int t = 0; t < NT - 4; t += 2) {                                           \
      TILE_E(t, 0, 1, true, 4);                                                     \
      TILE_E(t + 1, 1, 0, true, 4);                                                 \
    }                                                                               \
    TILE_E(NT - 4, 0, 1, true, 4);                                                  \
    TILE_E(NT - 3, 1, 0, false, 0);                                                 \
    TILE_E(NT - 2, 0, 1, false, -1);                                                \
    TILE_E(NT - 1, 1, 0, false, -1);                                                \
  } while (0)

#define KLOOP_O()                                                                   \
  do {                                                                              \
    for (int t = 0; t < NT - 4; t += 2) {                                           \
      TILE_O(t, 0, 1, true, 4);                                                     \
      TILE_O(t + 1, 1, 0, true, 4);                                                 \
    }                                                                               \
    TILE_O(NT - 4, 0, 1, true, 4);                                                  \
    TILE_O(NT - 3, 1, 0, false, 0);                                                 \
    TILE_O(NT - 2, 0, 1, false, -1);                                                \
    TILE_O(NT - 1, 1, 0, false, -1);                                                \
  } while (0)

  const float alpha = *alpha_p;
  const float beta  = *beta_p;
  const int col0 = bn + wc * 64 + frow;
  float bb4[4];
#pragma unroll
  for (int nj = 0; nj < 4; ++nj) bb4[nj] = beta * (float)bias[col0 + nj * 16];

  // Prologue round 0: stage tiles 0..2; vmcnt(4) -> tiles 0,1 landed.
  STAGE_A(0); STAGE_B(0);
  STAGE_A(1); STAGE_B(1);
  STAGE_A(2); STAGE_B(2);
  asm volatile("s_waitcnt vmcnt(4)" ::: "memory");
  __builtin_amdgcn_s_barrier();
  READ0(0, 0);

#pragma unroll 1
  for (int rnd = 0; rnd < 2; ++rnd) {
    if ((wave & 4) == 0) KLOOP_E();
    else                 KLOOP_O();

    if (rnd == 0) {
      // All own gloads drained (tail vmcnt(0)); all ds_reads consumed by
      // MFMA operand waits -> one barrier makes buf[0..2] safe to re-stage.
      __builtin_amdgcn_s_barrier();
      aoff[0] += RND_DELTA;
      aoff[1] += RND_DELTA;
      STAGE_A(0); STAGE_B(0);     // round-1 prologue: lands during epilogue
      STAGE_A(1); STAGE_B(1);
      STAGE_A(2); STAGE_B(2);
    }

    // Epilogue: D = rint(alpha*acc + beta*bias[n]).
    // C/D layout (16x16): col = lane&15, row = (lane>>4)*4 + reg.
    {
      const int rbase = bm + wr * 128 + (lane >> 4) * 4;
#pragma unroll
      for (int mi = 0; mi < 8; ++mi) {
#pragma unroll
        for (int r = 0; r < 4; ++r) {
          size_t rowoff = (size_t)(rbase + mi * 16 + r) * N_DIM;
#pragma unroll
          for (int nj = 0; nj < 4; ++nj) {
            out[rowoff + col0 + nj * 16] =
                (int)rintf(fmaf(alpha, (float)acc[mi][nj][r], bb4[nj]));
          }
        }
      }
    }

    if (rnd == 0) {
      // Drain stores + the 12 prologue loads (loads issued first, long
      // since landed under the store burst); then start round 1.
      asm volatile("s_waitcnt vmcnt(0)" ::: "memory");
      __builtin_amdgcn_s_barrier();
      READ0(0, 0);
#pragma unroll
      for (int i = 0; i < 8; ++i)
#pragma unroll
        for (int jj = 0; jj < 4; ++jj) acc[i][jj] = (v4i){0, 0, 0, 0};
      bm += 16 * BM;
    }
  }
#undef STAGE_A
#undef STAGE_B
#undef READ0
#undef READ1
#undef MFMA_LO
#undef MFMA_HI
#undef EVWAIT
#undef TILE_E
#undef TILE_O
#undef KLOOP_E
#undef KLOOP_O
}

// ---------------------------------------------------------------------------
// Safety fallback if ws is too small for the packed operands (slow but right).
// ---------------------------------------------------------------------------
__global__ void naive_kernel(const int* __restrict__ x, const int* __restrict__ w,
                             const int* __restrict__ bias,
                             const float* __restrict__ alpha_p,
                             const float* __restrict__ beta_p,
                             int* __restrict__ out) {
  size_t idx = (size_t)blockIdx.x * 256 + threadIdx.x;
  int m = (int)(idx / N_DIM);
  int n = (int)(idx % N_DIM);
  const int4* xr = (const int4*)(x + (size_t)m * K_DIM);
  const int4* wr = (const int4*)(w + (size_t)n * K_DIM);
  int acc = 0;
  for (int k = 0; k < K_DIM / 4; ++k) {
    int4 a = xr[k];
    int4 b = wr[k];
    acc += a.x * b.x + a.y * b.y + a.z * b.z + a.w * b.w;
  }
  out[idx] = (int)rintf(fmaf(*alpha_p, (float)acc, (*beta_p) * (float)bias[n]));
}

extern "C" void kernel_launch(void* const* d_in, const int* in_sizes, int n_in,
                              void* d_out, int out_size, void* d_ws, size_t ws_size,
                              hipStream_t stream) {
  const int*   x     = (const int*)d_in[0];
  const int*   w     = (const int*)d_in[1];
  const int*   bias  = (const int*)d_in[2];
  const float* alpha = (const float*)d_in[3];
  const float* beta  = (const float*)d_in[4];
  int* out = (int*)d_out;

  const size_t a8_bytes = (size_t)M_DIM * K_DIM;  // 32 MiB
  const size_t b8_bytes = (size_t)N_DIM * K_DIM;  // 16 MiB

  if (ws_size >= a8_bytes + b8_bytes) {
    char* A8 = (char*)d_ws;
    char* B8 = A8 + a8_bytes;
    const int nA = (int)(a8_bytes / 16);
    const int nTot = (int)((a8_bytes + b8_bytes) / 16);
    pack_both_kernel<<<2048, 256, 0, stream>>>(x, w, A8, B8, nA, nTot);
    const int nblk = (M_DIM / BM) * (N_DIM / BN) / 2;  // 256 persistent blocks
    gemm_i8_kernel<<<nblk, 512, 0, stream>>>(A8, B8, bias, alpha, beta, out);
  } else {
    naive_kernel<<<(M_DIM * (size_t)N_DIM) / 256, 256, 0, stream>>>(x, w, bias, alpha, beta, out);
  }
}

// Round 18
// 180.374 us; speedup vs baseline: 1.0476x; 1.0238x over previous
//
#include <hip/hip_runtime.h>
#include <hip/hip_bf16.h>
#include <stdint.h>

#define M_DIM 8192
#define N_DIM 4096
#define K_DIM 4096

#define BM 256
#define BN 256
#define BK 64                 // bytes of K per LDS tile = one mfma_i32_16x16x64_i8 K
#define NT (K_DIM / BK)       // 64 K-tiles
#define DEPTH 4               // circular LDS pipeline depth

typedef int v4i __attribute__((ext_vector_type(4)));

#define AS1C(p) ((const __attribute__((address_space(1))) void*)(p))
#define AS3(p)  ((__attribute__((address_space(3))) void*)(p))

// ---------------------------------------------------------------------------
// Fused pack pass: int32 (int8-range) -> int8 for BOTH operands, one launch.
// ---------------------------------------------------------------------------
__device__ __forceinline__ int pack4(int a, int b, int c, int d) {
  return (a & 0xff) | ((b & 0xff) << 8) | ((c & 0xff) << 16) | (d << 24);
}

__global__ void pack_both_kernel(const int* __restrict__ x, const int* __restrict__ w,
                                 char* __restrict__ A8, char* __restrict__ B8,
                                 int nA, int nTot) {
  int idx = blockIdx.x * blockDim.x + threadIdx.x;
  int stride = gridDim.x * blockDim.x;
  for (int i = idx; i < nTot; i += stride) {
    const int4* pin;
    int4* pout;
    if (i < nA) {
      pin  = (const int4*)x + 4 * (size_t)i;
      pout = (int4*)A8 + i;
    } else {
      int j = i - nA;
      pin  = (const int4*)w + 4 * (size_t)j;
      pout = (int4*)B8 + j;
    }
    int4 v0 = pin[0];
    int4 v1 = pin[1];
    int4 v2 = pin[2];
    int4 v3 = pin[3];
    int4 o;
    o.x = pack4(v0.x, v0.y, v0.z, v0.w);
    o.y = pack4(v1.x, v1.y, v1.z, v1.w);
    o.z = pack4(v2.x, v2.y, v2.z, v2.w);
    o.w = pack4(v3.x, v3.y, v3.z, v3.w);
    *pout = o;
  }
}

// ---------------------------------------------------------------------------
// FINAL CHAMPION (R15, measured: 127 us GEMM / 51.2% MfmaUtil / 0 conflicts /
// 180.6 us total): int8 GEMM, 256x256 tile, 8 waves (2Mx4N, per-wave 128x64),
// BK=64B, mfma_i32_16x16x64_i8, DEPTH=4 LDS ring, counted vmcnt (4/0), ONE
// barrier per K-tile, cross-tile register prefetch, setprio ON (R12: +6%),
// STATIC WAVE ANTI-PHASING (R15: +3%): even waves run reads->MFMA, odd waves
// run MFMA->reads, so the 2 waves per SIMD feed the LDS unit and MFMA pipe
// concurrently instead of alternating.
//
//   even: STAGE_A(t+3); READ1(t); MFMA_LO(t); STAGE_B(t+3); READ0(t+1);
//         MFMA_HI(t); vmcnt(4); barrier
//   odd:  MFMA_LO(t); STAGE_A(t+3); READ1(t); MFMA_HI(t); STAGE_B(t+3);
//         READ0(t+1); vmcnt(4); barrier
//
// Wait math (4 gloads/tile/thread): end-of-t vmcnt(4) -> tile t+2 landed
// => all reads during t+1 touch proven-landed buffers.  STAGE(t+3)
// overwrites buf[(t-1)&3] only after every wave's reads of t-1 drained
// (operand waits precede the end-of-(t-1) barrier).
// Bank conflicts: 16-row fragment pattern + chunk-XOR x(row)=((row>>1)&3)
// applied BOTH sides — measured 0 across 7 rounds.  32x32 MFMA rejected:
// intrinsic ~2x LDS read penalty (R3=R13: identical 1.26e7 conflicts under
// two different swizzles).  B-out-of-LDS rejected twice (R11 uncoalesced,
// R16 L2-thrash).  Persistence null (R17).
// ---------------------------------------------------------------------------
__global__ __launch_bounds__(512, 2) void gemm_i8_kernel(
    const char* __restrict__ A8, const char* __restrict__ B8,
    const int* __restrict__ bias, const float* __restrict__ alpha_p,
    const float* __restrict__ beta_p, int* __restrict__ out) {
  __shared__ alignas(16) char lds[DEPTH][BM * BK + BN * BK];  // 4 x 32 KiB

  const int tid  = threadIdx.x;
  const int lane = tid & 63;
  const int wave = tid >> 6;

  // XCD-aware bijective swizzle: 512 blocks, 64 consecutive per XCD.
  const int orig = blockIdx.x;
  const int swz  = (orig & 7) * (512 / 8) + (orig >> 3);
  const int bm   = (swz >> 4) * BM;  // 32 row-tiles
  const int bn   = (swz & 15) * BN;  // 16 col-tiles

  // Staging geometry: per operand tile 16 KB = 2 rounds x 512 thr x 16 B.
  // Pre-swizzled global chunk g = p ^ ((row>>1)&3) (both-sides swizzle).
  int aoff[2], boff[2], ldsoff[2];
#pragma unroll
  for (int i = 0; i < 2; ++i) {
    int linear = i * 8192 + tid * 16;
    int row = linear >> 6;           // 64 B rows
    int p   = (linear >> 4) & 3;
    int g   = p ^ ((row >> 1) & 3);
    ldsoff[i] = i * 8192 + wave * 1024;       // wave-uniform LDS base
    aoff[i] = (bm + row) * K_DIM + g * 16;
    boff[i] = (bn + row) * K_DIM + g * 16;
  }

#define STAGE_A(t)                                                                  \
  do {                                                                              \
    const char* ab_ = A8 + (size_t)(t) * BK;                                        \
    char* base_ = &lds[(t) & (DEPTH - 1)][0];                                       \
    _Pragma("unroll") for (int i_ = 0; i_ < 2; ++i_)                                \
      __builtin_amdgcn_global_load_lds(AS1C(ab_ + aoff[i_]),                        \
                                       AS3(base_ + ldsoff[i_]), 16, 0, 0);          \
  } while (0)

#define STAGE_B(t)                                                                  \
  do {                                                                              \
    const char* bb_ = B8 + (size_t)(t) * BK;                                        \
    char* base_ = &lds[(t) & (DEPTH - 1)][0];                                       \
    _Pragma("unroll") for (int i_ = 0; i_ < 2; ++i_)                                \
      __builtin_amdgcn_global_load_lds(AS1C(bb_ + boff[i_]),                        \
                                       AS3(base_ + 16384 + ldsoff[i_]), 16, 0, 0);  \
  } while (0)

  v4i acc[8][4];
#pragma unroll
  for (int i = 0; i < 8; ++i)
#pragma unroll
    for (int j = 0; j < 4; ++j) acc[i][j] = (v4i){0, 0, 0, 0};

  const int wr = wave >> 2;         // 0..1 (M half: 128 rows)
  const int wc = wave & 3;          // 0..3 (N quarter: 64 cols)
  const int frow = lane & 15;
  const int fchunk = lane >> 4;
  // swizzle XOR depends only on frow (rows differ by multiples of 16) -> lane-const
  const int swzoff = ((fchunk ^ ((frow >> 1) & 3)) << 4);

  // Ping-pong lo-fragment sets (static names, rule #20) + shared afhi.
  v4i bf0[4], aflo0[4], bf1[4], aflo1[4], afhi[4];

#define READ0(S, t)                                                                 \
  do {                                                                              \
    const char* base_ = &lds[(t) & (DEPTH - 1)][0];                                 \
    _Pragma("unroll") for (int nj = 0; nj < 4; ++nj)                                \
      bf##S[nj] = *(const v4i*)(base_ + 16384 + (wc * 64 + nj * 16 + frow) * 64 +   \
                                swzoff);                                            \
    _Pragma("unroll") for (int mi = 0; mi < 4; ++mi)                                \
      aflo##S[mi] = *(const v4i*)(base_ + (wr * 128 + mi * 16 + frow) * 64 +        \
                                  swzoff);                                          \
  } while (0)

#define READ1(t)                                                                    \
  do {                                                                              \
    const char* base_ = &lds[(t) & (DEPTH - 1)][0];                                 \
    _Pragma("unroll") for (int mi = 0; mi < 4; ++mi)                                \
      afhi[mi] = *(const v4i*)(base_ + (wr * 128 + (mi + 4) * 16 + frow) * 64 +     \
                               swzoff);                                             \
  } while (0)

#define MFMA_LO(S)                                                                  \
  do {                                                                              \
    __builtin_amdgcn_s_setprio(1);                                                  \
    _Pragma("unroll") for (int mi = 0; mi < 4; ++mi)                                \
      _Pragma("unroll") for (int nj = 0; nj < 4; ++nj)                              \
        acc[mi][nj] = __builtin_amdgcn_mfma_i32_16x16x64_i8(aflo##S[mi], bf##S[nj], \
                                                            acc[mi][nj], 0, 0, 0); \
    __builtin_amdgcn_s_setprio(0);                                                  \
  } while (0)

#define MFMA_HI(S)                                                                  \
  do {                                                                              \
    __builtin_amdgcn_s_setprio(1);                                                  \
    _Pragma("unroll") for (int mi = 0; mi < 4; ++mi)                                \
      _Pragma("unroll") for (int nj = 0; nj < 4; ++nj)                              \
        acc[mi + 4][nj] = __builtin_amdgcn_mfma_i32_16x16x64_i8(afhi[mi], bf##S[nj],\
                                                                acc[mi + 4][nj],   \
                                                                0, 0, 0);          \
    __builtin_amdgcn_s_setprio(0);                                                  \
  } while (0)

#define EVWAIT(EV)                                                                  \
  do {                                                                              \
    if ((EV) == 4) asm volatile("s_waitcnt vmcnt(4)" ::: "memory");                 \
    if ((EV) == 0) asm volatile("s_waitcnt vmcnt(0)" ::: "memory");                 \
    if ((EV) >= 0) __builtin_amdgcn_s_barrier();                                    \
  } while (0)

// Even group: LDS first, MFMA second.
#define TILE_E(t, C, N, STG, EV)                                                    \
  do {                                                                              \
    if (STG) STAGE_A((t) + 3);                                                      \
    READ1(t);                                                                       \
    MFMA_LO(C);                                                                     \
    if (STG) STAGE_B((t) + 3);                                                      \
    if ((t) + 1 < NT) READ0(N, (t) + 1);                                            \
    MFMA_HI(C);                                                                     \
    EVWAIT(EV);                                                                     \
  } while (0)

// Odd group: MFMA first, LDS second (anti-phase).
#define TILE_O(t, C, N, STG, EV)                                                    \
  do {                                                                              \
    MFMA_LO(C);                                                                     \
    if (STG) STAGE_A((t) + 3);                                                      \
    READ1(t);                                                                       \
    MFMA_HI(C);                                                                     \
    if (STG) STAGE_B((t) + 3);                                                      \
    if ((t) + 1 < NT) READ0(N, (t) + 1);                                            \
    EVWAIT(EV);                                                                     \
  } while (0)

  // Prologue (common): stage tiles 0..2; vmcnt(4) -> tiles 0,1 landed;
  // read tile-0 lo-frags so MFMA_LO(0) is resident for both groups.
  STAGE_A(0); STAGE_B(0);
  STAGE_A(1); STAGE_B(1);
  STAGE_A(2); STAGE_B(2);
  asm volatile("s_waitcnt vmcnt(4)" ::: "memory");
  __builtin_amdgcn_s_barrier();
  READ0(0, 0);

  if ((wave & 4) == 0) {
    for (int t = 0; t < NT - 4; t += 2) {   // t = 0..58: stages 3..62
      TILE_E(t, 0, 1, true, 4);
      TILE_E(t + 1, 1, 0, true, 4);
    }
    TILE_E(NT - 4, 0, 1, true, 4);          // t=60: stages tile 63
    TILE_E(NT - 3, 1, 0, false, 0);         // t=61: vmcnt(0) -> 63 landed
    TILE_E(NT - 2, 0, 1, false, -1);        // t=62: reads tile 63 frags
    TILE_E(NT - 1, 1, 0, false, -1);        // t=63
  } else {
    for (int t = 0; t < NT - 4; t += 2) {
      TILE_O(t, 0, 1, true, 4);
      TILE_O(t + 1, 1, 0, true, 4);
    }
    TILE_O(NT - 4, 0, 1, true, 4);
    TILE_O(NT - 3, 1, 0, false, 0);
    TILE_O(NT - 2, 0, 1, false, -1);
    TILE_O(NT - 1, 1, 0, false, -1);
  }

  // Epilogue: D = rint(alpha*acc + beta*bias[n]).
  // C/D layout (16x16): col = lane&15, row = (lane>>4)*4 + reg.
  const float alpha = *alpha_p;
  const float beta  = *beta_p;
  const int col0 = bn + wc * 64 + frow;
  float bb4[4];
#pragma unroll
  for (int nj = 0; nj < 4; ++nj) bb4[nj] = beta * (float)bias[col0 + nj * 16];

  const int rbase = bm + wr * 128 + (lane >> 4) * 4;
#pragma unroll
  for (int mi = 0; mi < 8; ++mi) {
#pragma unroll
    for (int r = 0; r < 4; ++r) {
      size_t rowoff = (size_t)(rbase + mi * 16 + r) * N_DIM;
#pragma unroll
      for (int nj = 0; nj < 4; ++nj) {
        out[rowoff + col0 + nj * 16] =
            (int)rintf(fmaf(alpha, (float)acc[mi][nj][r], bb4[nj]));
      }
    }
  }
#undef STAGE_A
#undef STAGE_B
#undef READ0
#undef READ1
#undef MFMA_LO
#undef MFMA_HI
#undef EVWAIT
#undef TILE_E
#undef TILE_O
}

// ---------------------------------------------------------------------------
// Safety fallback if ws is too small for the packed operands (slow but right).
// ---------------------------------------------------------------------------
__global__ void naive_kernel(const int* __restrict__ x, const int* __restrict__ w,
                             const int* __restrict__ bias,
                             const float* __restrict__ alpha_p,
                             const float* __restrict__ beta_p,
                             int* __restrict__ out) {
  size_t idx = (size_t)blockIdx.x * 256 + threadIdx.x;
  int m = (int)(idx / N_DIM);
  int n = (int)(idx % N_DIM);
  const int4* xr = (const int4*)(x + (size_t)m * K_DIM);
  const int4* wr = (const int4*)(w + (size_t)n * K_DIM);
  int acc = 0;
  for (int k = 0; k < K_DIM / 4; ++k) {
    int4 a = xr[k];
    int4 b = wr[k];
    acc += a.x * b.x + a.y * b.y + a.z * b.z + a.w * b.w;
  }
  out[idx] = (int)rintf(fmaf(*alpha_p, (float)acc, (*beta_p) * (float)bias[n]));
}

extern "C" void kernel_launch(void* const* d_in, const int* in_sizes, int n_in,
                              void* d_out, int out_size, void* d_ws, size_t ws_size,
                              hipStream_t stream) {
  const int*   x     = (const int*)d_in[0];
  const int*   w     = (const int*)d_in[1];
  const int*   bias  = (const int*)d_in[2];
  const float* alpha = (const float*)d_in[3];
  const float* beta  = (const float*)d_in[4];
  int* out = (int*)d_out;

  const size_t a8_bytes = (size_t)M_DIM * K_DIM;  // 32 MiB
  const size_t b8_bytes = (size_t)N_DIM * K_DIM;  // 16 MiB

  if (ws_size >= a8_bytes + b8_bytes) {
    char* A8 = (char*)d_ws;
    char* B8 = A8 + a8_bytes;
    const int nA = (int)(a8_bytes / 16);
    const int nTot = (int)((a8_bytes + b8_bytes) / 16);
    pack_both_kernel<<<2048, 256, 0, stream>>>(x, w, A8, B8, nA, nTot);
    const int nblk = (M_DIM / BM) * (N_DIM / BN);  // 32*16 = 512
    gemm_i8_kernel<<<nblk, 512, 0, stream>>>(A8, B8, bias, alpha, beta, out);
  } else {
    naive_kernel<<<(M_DIM * (size_t)N_DIM) / 256, 256, 0, stream>>>(x, w, bias, alpha, beta, out);
  }
}